// Round 4
// baseline (200.405 us; speedup 1.0000x reference)
//
#include <hip/hip_runtime.h>
#include <hip/hip_bf16.h>
#include <math.h>

#define MAXN    32
#define NPTS    16384
#define RSTRIDE 64              // ushorts per psi row (128 B): features 1..64, no head, no pad
#define BTA     64              // output tile rows per block
#define BTB     128             // output tile cols per block
#define NCHUNK  ((BTA + BTB) * RSTRIDE * 2 / 1024)   // 24 x 1KiB staging chunks
#define W0_OFF  (NPTS * RSTRIDE)                     // ushort offset of w0 stash in ws

typedef __attribute__((ext_vector_type(8))) short         bf16x8;
typedef __attribute__((ext_vector_type(4))) float         f32x4;
typedef __attribute__((ext_vector_type(4))) unsigned int  u32x4;

__device__ inline ushort f2bf(float f) {
    union { float f; unsigned u; } v; v.f = f;
    unsigned u = v.u;
    u += 0x7FFFu + ((u >> 16) & 1u);   // round-to-nearest-even
    return (ushort)(u >> 16);
}

// ---------------- kernel 1: psi rows (bf16, chunk-swizzled) -----------------
// Row r holds features 1..64 (head column dropped; its rank-1 w0 contribution
// is added via the MFMA C-initializer in gram_kernel). 8x16B chunks per row,
// stored at chunk slot (j ^ (r&7)) — the involution that makes gram's
// ds_read_b128 bank-balanced despite the 128B (bank-aligned) row stride.
__global__ __launch_bounds__(256) void psi_kernel(
    const float* __restrict__ xs, const float* __restrict__ logits,
    ushort* __restrict__ psi, float* __restrict__ w0scr)
{
    int pt = blockIdx.x * blockDim.x + threadIdx.x;
    if (pt >= NPTS) return;

    float x = xs[pt];
    x = fminf(1.0f, fmaxf(-1.0f, x));
    float s = sqrtf(fmaxf(0.0f, 1.0f - x * x));

    float m = -3.4e38f;
    #pragma unroll
    for (int n = 0; n <= MAXN; ++n) m = fmaxf(m, logits[n]);
    float sum = 0.0f;
    #pragma unroll
    for (int n = 0; n <= MAXN; ++n) sum += __expf(logits[n] - m);
    float inv = 1.0f / sum;

    if (pt == 0) w0scr[0] = __expf(logits[0] - m) * inv;   // w0, fp32-exact

    ushort tmp[RSTRIDE];
    float Tm1 = 1.0f, T = x;        // T_0, T_1
    float Um1 = 1.0f, U = 2.0f * x; // U_0, U_1
    float tx = 2.0f * x;
    #pragma unroll
    for (int n = 1; n <= MAXN; ++n) {
        float swn = sqrtf(__expf(logits[n] - m) * inv);
        tmp[2 * n - 2] = f2bf(swn * T);
        tmp[2 * n - 1] = f2bf(swn * (s * Um1));
        float Tn = tx * T - Tm1; Tm1 = T; T = Tn;
        float Un = tx * U - Um1; Um1 = U; U = Un;
    }

    u32x4* dst = (u32x4*)(psi + (size_t)pt * RSTRIDE);
    const u32x4* src = (const u32x4*)tmp;
    const int rx = pt & 7;
    #pragma unroll
    for (int j = 0; j < 8; ++j) dst[j ^ rx] = src[j];
}

// ---------------- kernel 2: gram = w0 + psi @ psi^T, 64x128 tile ------------
__device__ inline void load_lds16(const void* g, void* l) {
    __builtin_amdgcn_global_load_lds(
        (const __attribute__((address_space(1))) unsigned*)g,
        (__attribute__((address_space(3))) unsigned*)l, 16, 0, 0);
}

__global__ __launch_bounds__(256, 5) void gram_kernel(
    const ushort* __restrict__ psi, const float* __restrict__ w0scr,
    float* __restrict__ out)
{
    // bytes [0,8192): A panel (64 rows x 128B), [8192,24576): B panel (128 rows)
    // after compute: whole 32KB reused as fp32 [64][128] tile for the epilogue
    __shared__ float ldsF[BTA * BTB];

    const int tid  = threadIdx.x;
    const int w    = tid >> 6;     // wave 0..3: owns output rows w*16..w*16+15
    const int lane = tid & 63;
    const int bi   = blockIdx.y;   // 0..255 (row tile)
    const int bj   = blockIdx.x;   // 0..127 (col tile)

    const float w0 = w0scr[0];     // uniform scalar load (L2-cached)

    // ---- stage 24 x 1KiB chunks (A: 8, B: 16), linear LDS dest ----
    {
        const char* gA = (const char*)(psi + (size_t)bi * BTA * RSTRIDE);
        const char* gB = (const char*)(psi + (size_t)bj * BTB * RSTRIDE);
        char* lbase = (char*)ldsF;
        for (int q = w; q < NCHUNK; q += 4) {
            const char* src = (q < 8) ? (gA + q * 1024) : (gB + (q - 8) * 1024);
            load_lds16(src + lane * 16, lbase + q * 1024);
        }
    }
    __syncthreads();

    const int lr = lane & 15;      // operand row index within 16-tile
    const int lh = lane >> 4;      // k-chunk select within 32-k-step
    const int cq = lh * 4;         // output col quad (swapped D layout)

    const char* aRow   = (const char*)ldsF + (w * 16 + lr) * 128;
    const char* bPanel = (const char*)ldsF + 8192;

    f32x4 acc[8];
    #pragma unroll
    for (int ct = 0; ct < 8; ++ct) acc[ct] = (f32x4){w0, w0, w0, w0};  // rank-1 head term

    #pragma unroll
    for (int ks = 0; ks < 2; ++ks) {
        const int slot = (ks * 4 + lh);
        bf16x8 a = *(const bf16x8*)(aRow + ((slot ^ (lr & 7)) * 16));
        #pragma unroll
        for (int ct = 0; ct < 8; ++ct) {
            const char* bRow = bPanel + (ct * 16 + lr) * 128;
            bf16x8 b = *(const bf16x8*)(bRow + ((slot ^ (lr & 7)) * 16));
            // swapped operands: D row = lane&15, D col = (lane>>4)*4 + reg
            acc[ct] = __builtin_amdgcn_mfma_f32_16x16x32_bf16(b, a, acc[ct], 0, 0, 0);
        }
    }

    // ---- epilogue: transpose through LDS for 512B-contiguous stores ----
    __syncthreads();   // all waves done reading staged psi
    {
        const int row = w * 16 + lr;
        const int rxe = (row & 7) << 2;
        #pragma unroll
        for (int ct = 0; ct < 8; ++ct) {
            int col = (cq + ct * 16) ^ rxe;
            *(f32x4*)(ldsF + row * BTB + col) = acc[ct];
        }
    }
    __syncthreads();

    // ---- stream out: 8 passes, per-wave-instruction = 2 rows x 512 B ----
    {
        const int rsub = tid >> 5;         // 0..7
        const int col  = (tid & 31) * 4;   // 0..124
        #pragma unroll
        for (int p = 0; p < 8; ++p) {
            int row  = p * 8 + rsub;
            int colr = col ^ ((row & 7) << 2);
            f32x4 v = *(const f32x4*)(ldsF + row * BTB + colr);
            float* dst = out + (size_t)(bi * BTA + row) * NPTS + (size_t)bj * BTB + col;
            *(f32x4*)dst = v;
        }
    }
}

extern "C" void kernel_launch(void* const* d_in, const int* in_sizes, int n_in,
                              void* d_out, int out_size, void* d_ws, size_t ws_size,
                              hipStream_t stream) {
    const float* xs     = (const float*)d_in[0];
    const float* logits = (const float*)d_in[1];
    float* out          = (float*)d_out;
    ushort* psi         = (ushort*)d_ws;                  // NPTS*64*2 = 2 MB
    float*  w0scr       = (float*)((char*)d_ws + (size_t)W0_OFF * 2);

    psi_kernel<<<NPTS / 256, 256, 0, stream>>>(xs, logits, psi, w0scr);

    dim3 grid(NPTS / BTB, NPTS / BTA);
    gram_kernel<<<grid, 256, 0, stream>>>(psi, w0scr, out);
}

// Round 5
// 184.927 us; speedup vs baseline: 1.0837x; 1.0837x over previous
//
#include <hip/hip_runtime.h>
#include <hip/hip_bf16.h>
#include <math.h>

#define MAXN    32
#define NPTS    16384
#define RSTRIDE 64              // ushorts per psi row (128 B): features 1..64 (rank-1 head dropped)
#define BTA     64              // output tile rows per block
#define BTB     256             // output tile cols per block
#define NCHUNK  ((BTA + BTB) * RSTRIDE * 2 / 1024)   // 40 x 1KiB staging chunks
#define W0_OFF  (NPTS * RSTRIDE)                     // ushort offset of w0 stash in ws

typedef __attribute__((ext_vector_type(8))) short         bf16x8;
typedef __attribute__((ext_vector_type(4))) float         f32x4;
typedef __attribute__((ext_vector_type(4))) unsigned int  u32x4;

__device__ inline ushort f2bf(float f) {
    union { float f; unsigned u; } v; v.f = f;
    unsigned u = v.u;
    u += 0x7FFFu + ((u >> 16) & 1u);   // round-to-nearest-even
    return (ushort)(u >> 16);
}

// ---------------- kernel 1: psi rows (bf16, chunk-swizzled) -----------------
// Row r = 8x16B chunks, chunk j stored at slot (j ^ (r&7)) — involution that
// makes gram's ds_read_b128 bank-balanced despite the 128B row stride.
// Rows are redistributed through LDS so global stores are 1KB-contiguous.
__global__ __launch_bounds__(256) void psi_kernel(
    const float* __restrict__ xs, const float* __restrict__ logits,
    ushort* __restrict__ psi, float* __restrict__ w0scr)
{
    __shared__ ushort srow[256 * RSTRIDE];   // 32 KB

    const int tid = threadIdx.x;
    const int pt  = blockIdx.x * 256 + tid;

    float x = xs[pt];
    x = fminf(1.0f, fmaxf(-1.0f, x));
    float s = sqrtf(fmaxf(0.0f, 1.0f - x * x));

    float m = -3.4e38f;
    #pragma unroll
    for (int n = 0; n <= MAXN; ++n) m = fmaxf(m, logits[n]);
    float sum = 0.0f;
    #pragma unroll
    for (int n = 0; n <= MAXN; ++n) sum += __expf(logits[n] - m);
    float inv = 1.0f / sum;

    if (pt == 0) w0scr[0] = __expf(logits[0] - m) * inv;   // w0, fp32-exact

    ushort tmp[RSTRIDE];
    float Tm1 = 1.0f, T = x;        // T_0, T_1
    float Um1 = 1.0f, U = 2.0f * x; // U_0, U_1
    float tx = 2.0f * x;
    #pragma unroll
    for (int n = 1; n <= MAXN; ++n) {
        float swn = sqrtf(__expf(logits[n] - m) * inv);
        tmp[2 * n - 2] = f2bf(swn * T);
        tmp[2 * n - 1] = f2bf(swn * (s * Um1));
        float Tn = tx * T - Tm1; Tm1 = T; T = Tn;
        float Un = tx * U - Um1; Um1 = U; U = Un;
    }

    // swizzled write into LDS (bank-balanced: 8 dwords/bank per instruction)
    {
        u32x4* lrow = (u32x4*)(srow + tid * RSTRIDE);
        const u32x4* src = (const u32x4*)tmp;
        const int rx = tid & 7;
        #pragma unroll
        for (int j = 0; j < 8; ++j) lrow[j ^ rx] = src[j];
    }
    __syncthreads();

    // coalesced copy to global: per wave-instruction = 1 KB contiguous
    {
        const u32x4* ls = (const u32x4*)srow;
        u32x4* gd = (u32x4*)(psi + (size_t)blockIdx.x * 256 * RSTRIDE);
        #pragma unroll
        for (int i = 0; i < 8; ++i) gd[i * 256 + tid] = ls[i * 256 + tid];
    }
}

// ---------------- kernel 2: gram = w0 + psi @ psi^T, 64x256 tile ------------
__device__ inline void load_lds16(const void* g, void* l) {
    __builtin_amdgcn_global_load_lds(
        (const __attribute__((address_space(1))) unsigned*)g,
        (__attribute__((address_space(3))) unsigned*)l, 16, 0, 0);
}

__global__ __launch_bounds__(256) void gram_kernel(
    const ushort* __restrict__ psi, const float* __restrict__ w0scr,
    float* __restrict__ out)
{
    // staging: bytes [0,8192) = A panel (64 rows x 128B),
    //          bytes [8192,40960) = B panel (256 rows x 128B)
    // after compute: whole 64KB reused as fp32 [64][256] tile for the epilogue
    __shared__ float ldsF[BTA * BTB];   // 65536 B -> 2 blocks/CU

    const int tid  = threadIdx.x;
    const int w    = tid >> 6;     // wave 0..3: owns output rows w*16..w*16+15
    const int lane = tid & 63;
    const int bi   = blockIdx.y;   // 0..255 (row tile)
    const int bj   = blockIdx.x;   // 0..63  (col tile)

    const float w0 = w0scr[0];

    // ---- stage 40 x 1KiB chunks (A: 8, B: 32), linear LDS dest ----
    {
        const char* gA = (const char*)(psi + (size_t)bi * BTA * RSTRIDE);
        const char* gB = (const char*)(psi + (size_t)bj * BTB * RSTRIDE);
        char* lbase = (char*)ldsF;
        for (int q = w; q < NCHUNK; q += 4) {
            const char* src = (q < 8) ? (gA + q * 1024) : (gB + (q - 8) * 1024);
            load_lds16(src + lane * 16, lbase + q * 1024);
        }
    }
    __syncthreads();

    const int lr = lane & 15;      // operand row index within 16-tile
    const int lh = lane >> 4;      // k-chunk select within 32-k-step
    const int cq = lh * 4;         // output col quad (swapped D layout)

    const char* aRow   = (const char*)ldsF + (w * 16 + lr) * 128;
    const char* bPanel = (const char*)ldsF + 8192;

    f32x4 acc[16];
    #pragma unroll
    for (int ct = 0; ct < 16; ++ct) acc[ct] = (f32x4){w0, w0, w0, w0};  // rank-1 head term

    #pragma unroll
    for (int ks = 0; ks < 2; ++ks) {
        const int sx = ((ks * 4 + lh) ^ (lr & 7)) * 16;
        bf16x8 a = *(const bf16x8*)(aRow + sx);
        #pragma unroll
        for (int ct = 0; ct < 16; ++ct) {
            bf16x8 b = *(const bf16x8*)(bPanel + (ct * 16 + lr) * 128 + sx);
            // swapped operands: D row = lane&15, D col = (lane>>4)*4 + reg
            acc[ct] = __builtin_amdgcn_mfma_f32_16x16x32_bf16(b, a, acc[ct], 0, 0, 0);
        }
    }

    // ---- epilogue: transpose through LDS for 1KB-contiguous stores ----
    __syncthreads();   // all waves done reading staged psi
    {
        const int row = w * 16 + lr;
        const int rxe = (row & 7) << 2;
        #pragma unroll
        for (int ct = 0; ct < 16; ++ct) {
            int col = (cq + ct * 16) ^ rxe;
            *(f32x4*)(ldsF + row * BTB + col) = acc[ct];
        }
    }
    __syncthreads();

    // ---- stream out: 16 passes, per-wave-instruction = 1 row x 1024 B ----
    {
        #pragma unroll
        for (int p = 0; p < 16; ++p) {
            int row  = p * 4 + w;
            int colr = (lane * 4) ^ ((row & 7) << 2);
            f32x4 v = *(const f32x4*)(ldsF + row * BTB + colr);
            float* dst = out + (size_t)(bi * BTA + row) * NPTS + (size_t)bj * BTB + lane * 4;
            *(f32x4*)dst = v;
        }
    }
}

extern "C" void kernel_launch(void* const* d_in, const int* in_sizes, int n_in,
                              void* d_out, int out_size, void* d_ws, size_t ws_size,
                              hipStream_t stream) {
    const float* xs     = (const float*)d_in[0];
    const float* logits = (const float*)d_in[1];
    float* out          = (float*)d_out;
    ushort* psi         = (ushort*)d_ws;                  // NPTS*64*2 = 2 MB
    float*  w0scr       = (float*)((char*)d_ws + (size_t)W0_OFF * 2);

    psi_kernel<<<NPTS / 256, 256, 0, stream>>>(xs, logits, psi, w0scr);

    dim3 grid(NPTS / BTB, NPTS / BTA);
    gram_kernel<<<grid, 256, 0, stream>>>(psi, w0scr, out);
}